// Round 10
// baseline (51.434 us; speedup 1.0000x reference)
//
#include <hip/hip_runtime.h>
#include <hip/hip_cooperative_groups.h>
#include <math.h>

#define BB 32
#define HH 56
#define WW 56
#define CC 256
#define KS 7
#define NPIX (BB * HH * WW)   // 100352

// coop config: 256 blocks x 512 threads = 2048 waves; 49 px/wave == NPIX.
// __launch_bounds__(512, 1): 1 block/CU -> 2 waves/SIMD -> 256-VGPR tier,
// so a[49] (196 VGPRs) stays in registers (R9 failed because (512,2)
// clamped to 128 VGPRs and spilled).
#define NBLK 256
#define TPB 512
#define WPB 8                 // waves per block
#define PXW 49

// fallback (R6) config
#define NWPAIR (NPIX / 2)

typedef float vfloat4 __attribute__((ext_vector_type(4)));

namespace cg = cooperative_groups;

// ---------------------------------------------------------------------------
// DPP wave64 reductions: no DS ops, pure VALU.
// ---------------------------------------------------------------------------
template <int CTRL, int RM, int BM>
__device__ __forceinline__ float dpp_add(float v) {
    const int iv = __float_as_int(v);
    const int sh = __builtin_amdgcn_update_dpp(iv, iv, CTRL, RM, BM, false);
    return v + __int_as_float(sh);
}
template <int CTRL, int RM, int BM>
__device__ __forceinline__ float dpp_max(float v) {
    const int iv = __float_as_int(v);
    const int sh = __builtin_amdgcn_update_dpp(iv, iv, CTRL, RM, BM, false);
    return fmaxf(v, __int_as_float(sh));
}
__device__ __forceinline__ float wave_sum(float s) {
    s = dpp_add<0x111, 0xf, 0xf>(s);
    s = dpp_add<0x112, 0xf, 0xf>(s);
    s = dpp_add<0x114, 0xf, 0xe>(s);
    s = dpp_add<0x118, 0xf, 0xc>(s);
    s = dpp_add<0x142, 0xa, 0xf>(s);
    s = dpp_add<0x143, 0xc, 0xf>(s);
    return __int_as_float(__builtin_amdgcn_readlane(__float_as_int(s), 63));
}
__device__ __forceinline__ float wave_max(float m) {
    m = dpp_max<0x111, 0xf, 0xf>(m);
    m = dpp_max<0x112, 0xf, 0xf>(m);
    m = dpp_max<0x114, 0xf, 0xe>(m);
    m = dpp_max<0x118, 0xf, 0xc>(m);
    m = dpp_max<0x142, 0xa, 0xf>(m);
    m = dpp_max<0x143, 0xc, 0xf>(m);
    return __int_as_float(__builtin_amdgcn_readlane(__float_as_int(m), 63));
}

// ---------------------------------------------------------------------------
// Cooperative single kernel. Each wave owns 49 pixels; x stays in VGPRs
// across the grid sync so phase 2 re-reads NOTHING of x (saves 103MB VMEM).
// ---------------------------------------------------------------------------
__global__ __launch_bounds__(TPB, 1) void spatial_attn_all(
    const float* __restrict__ x,
    float2* __restrict__ pooled,
    const float2* __restrict__ cwv,
    float* __restrict__ out)
{
    const int wave = threadIdx.x >> 6;
    const int lane = threadIdx.x & 63;
    const int wid = blockIdx.x * WPB + wave;        // 0..2047

    const vfloat4* __restrict__ x4 = reinterpret_cast<const vfloat4*>(x);
    const size_t base = (size_t)wid * (PXW * 64) + lane;

    // ---- phase 1: load all 49 pixels into registers, pool ----
    vfloat4 a[PXW];
#pragma unroll
    for (int p = 0; p < PXW; ++p) {
        a[p] = x4[base + (size_t)p * 64];
    }

    const int pix0 = wid * PXW;
#pragma unroll
    for (int p = 0; p < PXW; ++p) {
        float s = (a[p].x + a[p].y) + (a[p].z + a[p].w);
        float m = fmaxf(fmaxf(a[p].x, a[p].y), fmaxf(a[p].z, a[p].w));
        s = wave_sum(s);
        m = wave_max(m);
        if (lane == 0) {
            pooled[pix0 + p] = make_float2(s * (1.0f / CC), m);
        }
    }

    cg::this_grid().sync();

    // ---- phase 2: conv + sigmoid from pooled; multiply from registers ----
    const bool active = lane < KS * KS;
    int ky = 0, kx = 0;
    float2 wgt = make_float2(0.0f, 0.0f);
    if (active) {
        ky = lane / KS;
        kx = lane - ky * KS;
        wgt = cwv[lane];
    }

#pragma unroll
    for (int p = 0; p < PXW; ++p) {
        const int pix = pix0 + p;
        const int wcol = pix % WW;
        const int t = pix / WW;
        const int hrow = t % HH;
        const int bimg = t / HH;

        float pa = 0.0f;
        if (active) {
            const int yy = hrow + ky - 3;
            const int xx = wcol + kx - 3;
            if ((unsigned)yy < HH && (unsigned)xx < WW) {
                const float2 pv = pooled[((size_t)bimg * HH + yy) * WW + xx];
                pa = fmaf(pv.x, wgt.x, pv.y * wgt.y);
            }
        }
        pa = wave_sum(pa);
        const float att = 1.0f / (1.0f + expf(-pa));

        reinterpret_cast<vfloat4*>(out)[base + (size_t)p * 64] = a[p] * att;
    }
}

// ---------------------------------------------------------------------------
// Fallback path (R6, 51.3us proven): two kernels, 2 px/wave.
// ---------------------------------------------------------------------------
__global__ __launch_bounds__(256) void pool_kernel(const float* __restrict__ x,
                                                   float4* __restrict__ pooled4) {
    const int wave = threadIdx.x >> 6;
    const int lane = threadIdx.x & 63;
    const int wid = blockIdx.x * 4 + wave;

    const size_t base = (size_t)wid * 128 + lane;
    const vfloat4 v0 = reinterpret_cast<const vfloat4*>(x)[base];
    const vfloat4 v1 = reinterpret_cast<const vfloat4*>(x)[base + 64];

    float s0 = (v0.x + v0.y) + (v0.z + v0.w);
    float m0 = fmaxf(fmaxf(v0.x, v0.y), fmaxf(v0.z, v0.w));
    float s1 = (v1.x + v1.y) + (v1.z + v1.w);
    float m1 = fmaxf(fmaxf(v1.x, v1.y), fmaxf(v1.z, v1.w));

    s0 = wave_sum(s0);
    s1 = wave_sum(s1);
    m0 = wave_max(m0);
    m1 = wave_max(m1);

    if (lane == 0) {
        pooled4[wid] = make_float4(s0 * (1.0f / CC), m0, s1 * (1.0f / CC), m1);
    }
}

__global__ __launch_bounds__(256) void fused_kernel(const float* __restrict__ x,
                                                    const float2* __restrict__ pooled,
                                                    const float2* __restrict__ cwv,
                                                    float* __restrict__ out) {
    const int wave = threadIdx.x >> 6;
    const int lane = threadIdx.x & 63;
    const int wid = blockIdx.x * 4 + wave;

    const size_t base = (size_t)wid * 128 + lane;
    const vfloat4 v0 = reinterpret_cast<const vfloat4*>(x)[base];
    const vfloat4 v1 = reinterpret_cast<const vfloat4*>(x)[base + 64];

    const int pix0 = wid * 2;
    const int wcol0 = pix0 % WW;
    const int t = pix0 / WW;
    const int hrow = t % HH;
    const int b = t / HH;

    float pa = 0.0f, pb = 0.0f;
    if (lane < KS * KS) {
        const int ky = lane / KS;
        const int kx = lane - ky * KS;
        const int yy = hrow + ky - 3;
        if (yy >= 0 && yy < HH) {
            const float2* __restrict__ row = pooled + ((size_t)b * HH + yy) * WW;
            const float2 w = cwv[lane];
            const int xx0 = wcol0 + kx - 3;
            const int xx1 = xx0 + 1;
            if (xx0 >= 0 && xx0 < WW) {
                const float2 p = row[xx0];
                pa = fmaf(p.x, w.x, p.y * w.y);
            }
            if (xx1 >= 0 && xx1 < WW) {
                const float2 p = row[xx1];
                pb = fmaf(p.x, w.x, p.y * w.y);
            }
        }
    }
    pa = wave_sum(pa);
    pb = wave_sum(pb);
    const float att0 = 1.0f / (1.0f + expf(-pa));
    const float att1 = 1.0f / (1.0f + expf(-pb));

    reinterpret_cast<vfloat4*>(out)[base]      = v0 * att0;
    reinterpret_cast<vfloat4*>(out)[base + 64] = v1 * att1;
}

extern "C" void kernel_launch(void* const* d_in, const int* in_sizes, int n_in,
                              void* d_out, int out_size, void* d_ws, size_t ws_size,
                              hipStream_t stream) {
    const float* x = (const float*)d_in[0];
    const float2* cw = (const float2*)d_in[1];
    float* out = (float*)d_out;
    float2* pooled = (float2*)d_ws;

    // Host-side, capture-safe, deterministic occupancy check: only take the
    // cooperative path if the runtime agrees >=1 block/CU fits (512 thr).
    int maxb = 0;
    hipError_t oe = hipOccupancyMaxActiveBlocksPerMultiprocessor(
        &maxb, (const void*)spatial_attn_all, TPB, 0);

    if (oe == hipSuccess && maxb >= 1) {
        void* args[] = {(void*)&x, (void*)&pooled, (void*)&cw, (void*)&out};
        hipLaunchCooperativeKernel((void*)spatial_attn_all, dim3(NBLK), dim3(TPB),
                                   args, 0, stream);
    } else {
        const int grid = NWPAIR / 4;  // 12544 blocks
        pool_kernel<<<grid, 256, 0, stream>>>(x, (float4*)pooled);
        fused_kernel<<<grid, 256, 0, stream>>>(x, pooled, cw, out);
    }
}

// Round 11
// 51.345 us; speedup vs baseline: 1.0017x; 1.0017x over previous
//
#include <hip/hip_runtime.h>
#include <hip/hip_cooperative_groups.h>
#include <math.h>

#define BB 32
#define HH 56
#define WW 56
#define CC 256
#define KS 7
#define NPIX (BB * HH * WW)   // 100352

// coop config: 256 blocks x 512 threads = 2048 waves; 49 px/wave == NPIX.
// __launch_bounds__(512, 1): 1 block/CU -> 2 waves/SIMD -> 256-VGPR tier.
#define NBLK 256
#define TPB 512
#define WPB 8                 // waves per block
#define PXW 49

// fallback (R6) config
#define NWPAIR (NPIX / 2)

typedef float vfloat4 __attribute__((ext_vector_type(4)));

namespace cg = cooperative_groups;

// ---------------------------------------------------------------------------
// DPP wave64 reductions: no DS ops, pure VALU.
// ---------------------------------------------------------------------------
template <int CTRL, int RM, int BM>
__device__ __forceinline__ float dpp_add(float v) {
    const int iv = __float_as_int(v);
    const int sh = __builtin_amdgcn_update_dpp(iv, iv, CTRL, RM, BM, false);
    return v + __int_as_float(sh);
}
template <int CTRL, int RM, int BM>
__device__ __forceinline__ float dpp_max(float v) {
    const int iv = __float_as_int(v);
    const int sh = __builtin_amdgcn_update_dpp(iv, iv, CTRL, RM, BM, false);
    return fmaxf(v, __int_as_float(sh));
}
__device__ __forceinline__ float wave_sum(float s) {
    s = dpp_add<0x111, 0xf, 0xf>(s);
    s = dpp_add<0x112, 0xf, 0xf>(s);
    s = dpp_add<0x114, 0xf, 0xe>(s);
    s = dpp_add<0x118, 0xf, 0xc>(s);
    s = dpp_add<0x142, 0xa, 0xf>(s);
    s = dpp_add<0x143, 0xc, 0xf>(s);
    return __int_as_float(__builtin_amdgcn_readlane(__float_as_int(s), 63));
}
__device__ __forceinline__ float wave_max(float m) {
    m = dpp_max<0x111, 0xf, 0xf>(m);
    m = dpp_max<0x112, 0xf, 0xf>(m);
    m = dpp_max<0x114, 0xf, 0xe>(m);
    m = dpp_max<0x118, 0xf, 0xc>(m);
    m = dpp_max<0x142, 0xa, 0xf>(m);
    m = dpp_max<0x143, 0xc, 0xf>(m);
    return __int_as_float(__builtin_amdgcn_readlane(__float_as_int(m), 63));
}

// ---------------------------------------------------------------------------
// Cooperative single kernel. Each wave owns 49 pixels; x is loaded ONCE into
// VGPRs and PINNED live across the grid sync (asm "+v" makes the values
// opaque so the compiler cannot rematerialize the loads in phase 2 — which
// is exactly what it did in R10, VGPR_Count=108, re-reading 103MB of x).
// ---------------------------------------------------------------------------
__global__ __launch_bounds__(TPB, 1) void spatial_attn_all(
    const float* __restrict__ x,
    float2* __restrict__ pooled,
    const float2* __restrict__ cwv,
    float* __restrict__ out)
{
    const int wave = threadIdx.x >> 6;
    const int lane = threadIdx.x & 63;
    const int wid = blockIdx.x * WPB + wave;        // 0..2047

    const vfloat4* __restrict__ x4 = reinterpret_cast<const vfloat4*>(x);
    const size_t base = (size_t)wid * (PXW * 64) + lane;

    // ---- phase 1: load all 49 pixels into registers, pool ----
    vfloat4 a[PXW];
#pragma unroll
    for (int p = 0; p < PXW; ++p) {
        a[p] = x4[base + (size_t)p * 64];
    }

    const int pix0 = wid * PXW;
#pragma unroll
    for (int p = 0; p < PXW; ++p) {
        float s = (a[p].x + a[p].y) + (a[p].z + a[p].w);
        float m = fmaxf(fmaxf(a[p].x, a[p].y), fmaxf(a[p].z, a[p].w));
        s = wave_sum(s);
        m = wave_max(m);
        if (lane == 0) {
            pooled[pix0 + p] = make_float2(s * (1.0f / CC), m);
        }
    }

    cg::this_grid().sync();

    // ---- pin: force a[] to stay in VGPRs across the sync (no remat) ----
#pragma unroll
    for (int p = 0; p < PXW; ++p) {
        asm volatile("" : "+v"(a[p]));
    }

    // ---- phase 2: conv + sigmoid from pooled; multiply from registers ----
    const bool active = lane < KS * KS;
    int ky = 0, kx = 0;
    float2 wgt = make_float2(0.0f, 0.0f);
    if (active) {
        ky = lane / KS;
        kx = lane - ky * KS;
        wgt = cwv[lane];
    }

#pragma unroll
    for (int p = 0; p < PXW; ++p) {
        const int pix = pix0 + p;
        const int wcol = pix % WW;
        const int t = pix / WW;
        const int hrow = t % HH;
        const int bimg = t / HH;

        float pa = 0.0f;
        if (active) {
            const int yy = hrow + ky - 3;
            const int xx = wcol + kx - 3;
            if ((unsigned)yy < HH && (unsigned)xx < WW) {
                const float2 pv = pooled[((size_t)bimg * HH + yy) * WW + xx];
                pa = fmaf(pv.x, wgt.x, pv.y * wgt.y);
            }
        }
        pa = wave_sum(pa);
        const float att = 1.0f / (1.0f + expf(-pa));

        reinterpret_cast<vfloat4*>(out)[base + (size_t)p * 64] = a[p] * att;
    }
}

// ---------------------------------------------------------------------------
// Fallback path (R6, 51.3us proven): two kernels, 2 px/wave.
// ---------------------------------------------------------------------------
__global__ __launch_bounds__(256) void pool_kernel(const float* __restrict__ x,
                                                   float4* __restrict__ pooled4) {
    const int wave = threadIdx.x >> 6;
    const int lane = threadIdx.x & 63;
    const int wid = blockIdx.x * 4 + wave;

    const size_t base = (size_t)wid * 128 + lane;
    const vfloat4 v0 = reinterpret_cast<const vfloat4*>(x)[base];
    const vfloat4 v1 = reinterpret_cast<const vfloat4*>(x)[base + 64];

    float s0 = (v0.x + v0.y) + (v0.z + v0.w);
    float m0 = fmaxf(fmaxf(v0.x, v0.y), fmaxf(v0.z, v0.w));
    float s1 = (v1.x + v1.y) + (v1.z + v1.w);
    float m1 = fmaxf(fmaxf(v1.x, v1.y), fmaxf(v1.z, v1.w));

    s0 = wave_sum(s0);
    s1 = wave_sum(s1);
    m0 = wave_max(m0);
    m1 = wave_max(m1);

    if (lane == 0) {
        pooled4[wid] = make_float4(s0 * (1.0f / CC), m0, s1 * (1.0f / CC), m1);
    }
}

__global__ __launch_bounds__(256) void fused_kernel(const float* __restrict__ x,
                                                    const float2* __restrict__ pooled,
                                                    const float2* __restrict__ cwv,
                                                    float* __restrict__ out) {
    const int wave = threadIdx.x >> 6;
    const int lane = threadIdx.x & 63;
    const int wid = blockIdx.x * 4 + wave;

    const size_t base = (size_t)wid * 128 + lane;
    const vfloat4 v0 = reinterpret_cast<const vfloat4*>(x)[base];
    const vfloat4 v1 = reinterpret_cast<const vfloat4*>(x)[base + 64];

    const int pix0 = wid * 2;
    const int wcol0 = pix0 % WW;
    const int t = pix0 / WW;
    const int hrow = t % HH;
    const int b = t / HH;

    float pa = 0.0f, pb = 0.0f;
    if (lane < KS * KS) {
        const int ky = lane / KS;
        const int kx = lane - ky * KS;
        const int yy = hrow + ky - 3;
        if (yy >= 0 && yy < HH) {
            const float2* __restrict__ row = pooled + ((size_t)b * HH + yy) * WW;
            const float2 w = cwv[lane];
            const int xx0 = wcol0 + kx - 3;
            const int xx1 = xx0 + 1;
            if (xx0 >= 0 && xx0 < WW) {
                const float2 p = row[xx0];
                pa = fmaf(p.x, w.x, p.y * w.y);
            }
            if (xx1 >= 0 && xx1 < WW) {
                const float2 p = row[xx1];
                pb = fmaf(p.x, w.x, p.y * w.y);
            }
        }
    }
    pa = wave_sum(pa);
    pb = wave_sum(pb);
    const float att0 = 1.0f / (1.0f + expf(-pa));
    const float att1 = 1.0f / (1.0f + expf(-pb));

    reinterpret_cast<vfloat4*>(out)[base]      = v0 * att0;
    reinterpret_cast<vfloat4*>(out)[base + 64] = v1 * att1;
}

extern "C" void kernel_launch(void* const* d_in, const int* in_sizes, int n_in,
                              void* d_out, int out_size, void* d_ws, size_t ws_size,
                              hipStream_t stream) {
    const float* x = (const float*)d_in[0];
    const float2* cw = (const float2*)d_in[1];
    float* out = (float*)d_out;
    float2* pooled = (float2*)d_ws;

    // Host-side, capture-safe, deterministic occupancy check: only take the
    // cooperative path if the runtime agrees >=1 block/CU fits (512 thr).
    int maxb = 0;
    hipError_t oe = hipOccupancyMaxActiveBlocksPerMultiprocessor(
        &maxb, (const void*)spatial_attn_all, TPB, 0);

    if (oe == hipSuccess && maxb >= 1) {
        void* args[] = {(void*)&x, (void*)&pooled, (void*)&cw, (void*)&out};
        hipLaunchCooperativeKernel((void*)spatial_attn_all, dim3(NBLK), dim3(TPB),
                                   args, 0, stream);
    } else {
        const int grid = NWPAIR / 4;  // 12544 blocks
        pool_kernel<<<grid, 256, 0, stream>>>(x, (float4*)pooled);
        fused_kernel<<<grid, 256, 0, stream>>>(x, pooled, cw, out);
    }
}